// Round 2
// baseline (465.572 us; speedup 1.0000x reference)
//
#include <hip/hip_runtime.h>

#define CACHELINE 64
#define THRESH 0.05f

__global__ __launch_bounds__(256) void cluster_kernel(
        const float* __restrict__ x, float* __restrict__ out, long long nrows) {
    long long row = (long long)blockIdx.x * blockDim.x + threadIdx.x;
    if (row >= nrows) return;

    const float4* __restrict__ p = reinterpret_cast<const float4*>(x + row * CACHELINE);
    float v[CACHELINE];

    // Load 64 floats as 16x float4 (16B/lane per instruction).
    #pragma unroll
    for (int k = 0; k < CACHELINE / 4; ++k) {
        float4 t = p[k];
        v[4 * k + 0] = t.x;
        v[4 * k + 1] = t.y;
        v[4 * k + 2] = t.z;
        v[4 * k + 3] = t.w;
    }

    // Sequential clustering recurrence (exact vs reference scan):
    //   final[j] = final[idx*], idx* = min{ idx < j : |x_orig[j]-final[idx]| <= thr }
    //            = x_orig[j] if no such idx.
    // Downward branchless scan => lowest matching idx wins. Full unroll =>
    // all indices compile-time => v[] stays in VGPRs (no scratch).
    #pragma unroll
    for (int j = 1; j < CACHELINE; ++j) {
        const float xj = v[j];   // original value of column j (frozen until clustered)
        float r = xj;
        #pragma unroll
        for (int idx = j - 1; idx >= 0; --idx) {
            // 3 VALU: v_sub_f32, v_cmp_le_f32 (abs src modifier), v_cndmask_b32
            r = (fabsf(xj - v[idx]) <= THRESH) ? v[idx] : r;
        }
        v[j] = r;
    }

    // Store 16x float4.
    float4* __restrict__ o = reinterpret_cast<float4*>(out + row * CACHELINE);
    #pragma unroll
    for (int k = 0; k < CACHELINE / 4; ++k) {
        o[k] = make_float4(v[4 * k + 0], v[4 * k + 1], v[4 * k + 2], v[4 * k + 3]);
    }
}

extern "C" void kernel_launch(void* const* d_in, const int* in_sizes, int n_in,
                              void* d_out, int out_size, void* d_ws, size_t ws_size,
                              hipStream_t stream) {
    const float* x = (const float*)d_in[0];
    float* out = (float*)d_out;
    long long n = in_sizes[0];
    long long nrows = n / CACHELINE;          // 1,048,576 for the bench shape
    int block = 256;
    long long grid = (nrows + block - 1) / block;  // 4096 blocks
    cluster_kernel<<<(dim3)(unsigned)grid, block, 0, stream>>>(x, out, nrows);
}

// Round 5
// 464.736 us; speedup vs baseline: 1.0018x; 1.0018x over previous
//
#include <hip/hip_runtime.h>

#define CACHELINE 64
#define THRESH 0.05f

// doCol<J>: column J's scan over idx in [0, J). Trip count is the
// compile-time constant J, so #pragma unroll fully unrolls and every v[]
// index is a literal -> SROA keeps v[] entirely in VGPRs (no scratch).
// Downward scan + branchless cndmask => lowest matching idx wins:
//   final[J] = final[idx*], idx* = min{ idx < J : |x_orig[J]-final[idx]| <= thr }
//            = x_orig[J] if none.
template<int J>
__device__ __forceinline__ void doCol(float (&v)[CACHELINE]) {
    const float xj = v[J];
    float r = xj;
    #pragma unroll
    for (int idx = J - 1; idx >= 0; --idx) {
        // 3 VALU: v_sub_f32, v_cmp_le_f32 (abs modifier), v_cndmask_b32
        r = (fabsf(xj - v[idx]) <= THRESH) ? v[idx] : r;
    }
    v[J] = r;
}

template<int J>
__device__ __forceinline__ void scanAll(float (&v)[CACHELINE]) {
    if constexpr (J < CACHELINE) {
        doCol<J>(v);
        scanAll<J + 1>(v);
    }
}

__global__ __launch_bounds__(256) void cluster_kernel(
        const float* __restrict__ x, float* __restrict__ out, long long nrows) {
    long long row = (long long)blockIdx.x * blockDim.x + threadIdx.x;
    if (row >= nrows) return;

    const float4* __restrict__ p = reinterpret_cast<const float4*>(x + row * CACHELINE);
    float v[CACHELINE];

    // Load 64 floats as 16x float4 (16B/lane per instruction).
    #pragma unroll
    for (int k = 0; k < CACHELINE / 4; ++k) {
        float4 t = p[k];
        v[4 * k + 0] = t.x;
        v[4 * k + 1] = t.y;
        v[4 * k + 2] = t.z;
        v[4 * k + 3] = t.w;
    }

    scanAll<1>(v);   // column 0 never changes

    // Store 16x float4.
    float4* __restrict__ o = reinterpret_cast<float4*>(out + row * CACHELINE);
    #pragma unroll
    for (int k = 0; k < CACHELINE / 4; ++k) {
        o[k] = make_float4(v[4 * k + 0], v[4 * k + 1], v[4 * k + 2], v[4 * k + 3]);
    }
}

extern "C" void kernel_launch(void* const* d_in, const int* in_sizes, int n_in,
                              void* d_out, int out_size, void* d_ws, size_t ws_size,
                              hipStream_t stream) {
    const float* x = (const float*)d_in[0];
    float* out = (float*)d_out;
    long long n = in_sizes[0];
    long long nrows = n / CACHELINE;          // 1,048,576 for the bench shape
    int block = 256;
    long long grid = (nrows + block - 1) / block;  // 4096 blocks
    cluster_kernel<<<(dim3)(unsigned)grid, block, 0, stream>>>(x, out, nrows);
}